// Round 1
// baseline (589.553 us; speedup 1.0000x reference)
//
#include <hip/hip_runtime.h>
#include <stdint.h>

#define NNODES 64
#define NVIS   16
#define NHID   48
#define NSTEPS 20
#define BATCH  65536
#define EDIM   512

// ---------------- Threefry-2x32 (20 rounds), exactly as JAX/random123 ----------------
__device__ __forceinline__ void tf2x32(uint32_t k0, uint32_t k1,
                                       uint32_t x0, uint32_t x1,
                                       uint32_t& o0, uint32_t& o1) {
  const uint32_t ks0 = k0, ks1 = k1, ks2 = k0 ^ k1 ^ 0x1BD11BDAu;
  x0 += ks0; x1 += ks1;
  const int rotA[4] = {13, 15, 26, 6};
  const int rotB[4] = {17, 29, 16, 24};
#pragma unroll
  for (int i = 0; i < 5; ++i) {
#pragma unroll
    for (int r = 0; r < 4; ++r) {
      const int rot = (i & 1) ? rotB[r] : rotA[r];
      x0 += x1;
      x1 = (x1 << rot) | (x1 >> (32 - rot));
      x1 ^= x0;
    }
    // x0 += ks[(i+1)%3]; x1 += ks[(i+2)%3] + (i+1)
    const uint32_t i0 = (i == 0 || i == 3) ? ks1 : (i == 1 || i == 4) ? ks2 : ks0;
    const uint32_t i1 = (i == 0 || i == 3) ? ks2 : (i == 1 || i == 4) ? ks0 : ks1;
    x0 += i0;
    x1 += i1 + (uint32_t)(i + 1);
  }
  o0 = x0; o1 = x1;
}

// partitionable random_bits for 32-bit: xor of the two cipher words at counter (0, n)
__device__ __forceinline__ uint32_t rbits32(uint32_t k0, uint32_t k1, uint32_t n) {
  uint32_t a, b;
  tf2x32(k0, k1, 0u, n, a, b);
  return a ^ b;
}

// JAX uniform [0,1): bitcast((bits>>9)|0x3f800000) - 1.0  (exact)
__device__ __forceinline__ float u01(uint32_t bits) {
  return __uint_as_float((bits >> 9) | 0x3f800000u) - 1.0f;
}

// ---------------- XLA CPU expf (llvm_ir_runtime GenerateVF32Exp, Cephes) ----------------
__device__ __forceinline__ float xla_expf(float x) {
#pragma clang fp contract(off)
  x = fminf(x, 88.3762626647950f);
  x = fmaxf(x, -88.3762626647949f);
  float fx = floorf(fmaf(x, 1.44269504088896341f, 0.5f));
  float tmp = 0.693359375f * fx;      // separate mul (NOT fused) like XLA
  float z   = -2.12194440e-4f * fx;   // separate mul
  float xr  = x - tmp;
  xr = xr - z;
  float zz = xr * xr;
  float y = fmaf(xr, 1.9875691500e-4f, 1.3981999507e-3f);
  y = fmaf(y, xr, 8.3334519073e-3f);
  y = fmaf(y, xr, 4.1665795894e-2f);
  y = fmaf(y, xr, 1.6666665459e-1f);
  y = fmaf(y, xr, 5.0000001201e-1f);
  y = fmaf(y, zz, xr);
  y = y + 1.0f;
  int m = (int)fx;
  float e2 = __int_as_float((m + 127) << 23);
  return y * e2;
}

// jax.nn.sigmoid -> lax.logistic -> 1/(1+exp(-x)) (JAX MLIR lowering), IEEE f32 divide
__device__ __forceinline__ float xla_sigmoid(float a) {
#pragma clang fp contract(off)
  float e = xla_expf(-a);
  return 1.0f / (1.0f + e);
}

// ---------------- column dot: replicate Eigen GEMM per-element rounding ----------------
// act_j = sum_{k=0..63} s_k * W[k][j], sequential k, single acc, fused fma.
// s_k = sv for k<16; s_k in {0,1} for k>=16: fma(1,w,a)==a+w, fma(0,w,a)==a (exact).
__device__ __forceinline__ void dot_cols(const float (*Wl)[NNODES], int lane,
                                         float sv0, float sv1,
                                         unsigned long long m0, unsigned long long m1,
                                         float& acc0, float& acc1) {
#pragma clang fp contract(off)
  float a0 = 0.0f, a1 = 0.0f;
#pragma unroll
  for (int k = 0; k < NVIS; ++k) {
    float w = Wl[k][lane];
    a0 = fmaf(sv0, w, a0);
    a1 = fmaf(sv1, w, a1);
  }
#pragma unroll
  for (int k = NVIS; k < NNODES; ++k) {
    float w = Wl[k][lane];
    float t0 = a0 + w, t1 = a1 + w;
    a0 = ((m0 >> k) & 1ull) ? t0 : a0;
    a1 = ((m1 >> k) & 1ull) ? t1 : a1;
  }
  acc0 = a0; acc1 = a1;
}

// ---------------- kernel 1: partial column sums of embedding (b has loose tolerance) ----
__global__ void colsum_kernel(const float* __restrict__ emb, float* __restrict__ partials,
                              int nblk) {
  int col = threadIdx.x;           // 512 threads = 512 columns
  float acc = 0.0f;
  for (int r = blockIdx.x; r < BATCH; r += nblk)
    acc += emb[(size_t)r * EDIM + col];
  partials[(size_t)blockIdx.x * EDIM + col] = acc;
}

// ---------------- kernel 2: finish b, derive all threefry keys ----------------
__global__ void prep_kernel(const float* __restrict__ pca,
                            const float* __restrict__ partials, int nblk,
                            float* __restrict__ bvec, unsigned* __restrict__ keys) {
  __shared__ float cs[EDIM];
  int t = threadIdx.x;             // 512 threads
  float a = 0.0f;
  for (int i = 0; i < nblk; ++i) a += partials[(size_t)i * EDIM + t];
  cs[t] = a;
  __syncthreads();
  if (t < NNODES) {
    float bj = 0.0f;
    if (t < NVIS) {
      for (int e = 0; e < EDIM; ++e) bj = fmaf(cs[e], pca[e * NVIS + t], bj);
      bj *= (1.0f / 65536.0f);
    }
    bvec[t] = bj;                  // b[j]=0 for hidden j — matches reference exactly
  }
  if (t == 0) {
    // root key(42) = (0,42); foldlike split: key_i = cipher(parent, (0, i))
    uint32_t ki0, ki1, ks0, ks1;
    tf2x32(0u, 42u, 0u, 0u, ki0, ki1);   // k_init
    tf2x32(0u, 42u, 0u, 1u, ks0, ks1);   // k_scan
    keys[0] = ki0; keys[1] = ki1;
    for (int s = 0; s < NSTEPS; ++s) {
      uint32_t y0, y1;
      tf2x32(ks0, ks1, 0u, (uint32_t)s, y0, y1);
      keys[2 + 2 * s] = y0;
      keys[3 + 2 * s] = y1;
    }
  }
}

// ---------------- kernel 3: 20-step Gibbs chain + energy, 1 wave = 2 rows ----------------
__global__ __launch_bounds__(256) void gibbs_kernel(const float* __restrict__ reward,
                                                    const float* __restrict__ quadratic,
                                                    const float* __restrict__ bvec,
                                                    const unsigned* __restrict__ keys,
                                                    float* __restrict__ out) {
  __shared__ float Wl[NNODES][NNODES];   // Wsym = Q + Q^T, 16KB
  __shared__ unsigned kl[2 + 2 * NSTEPS];
  __shared__ float bl[NNODES];

  int tid = threadIdx.x;
  for (int i = tid; i < NNODES * NNODES; i += 256) {
    int k = i >> 6, j = i & 63;
    Wl[k][j] = quadratic[i] + quadratic[j * NNODES + k];  // exact f32 add, matches jnp
  }
  if (tid < 2 + 2 * NSTEPS) kl[tid] = keys[tid];
  if (tid < NNODES) bl[tid] = bvec[tid];
  __syncthreads();

  const int wave = tid >> 6, lane = tid & 63;
  const int pairIdx = blockIdx.x * 4 + wave;
  const int r0 = pairIdx * 2, r1 = r0 + 1;

  const float rw0 = reward[r0], rw1 = reward[r1];
  const float sv0 = xla_sigmoid(rw0 * 2.0f);
  const float sv1 = xla_sigmoid(rw1 * 2.0f);

  // hidden0 = bernoulli(k_init, 0.5, (B,48)): bit = (rbits32 >> 31) == 0  (u < 0.5)
  unsigned long long m0, m1;
  {
    bool hb0 = false, hb1 = false;
    if (lane >= NVIS) {
      int jh = lane - NVIS;
      hb0 = (rbits32(kl[0], kl[1], (uint32_t)(r0 * NHID + jh)) >> 31) == 0u;
      hb1 = (rbits32(kl[0], kl[1], (uint32_t)(r1 * NHID + jh)) >> 31) == 0u;
    }
    m0 = __ballot(hb0);
    m1 = __ballot(hb1);
  }

  for (int t = 0; t < NSTEPS; ++t) {
    const unsigned kt0 = kl[2 + 2 * t], kt1 = kl[3 + 2 * t];
    float acc0, acc1;
    dot_cols(Wl, lane, sv0, sv1, m0, m1, acc0, acc1);
    // b[j] = 0 exactly for hidden j, and visible p's are discarded -> no b add needed
    float p0 = xla_sigmoid(acc0);
    float p1 = xla_sigmoid(acc1);
    float u0 = u01(rbits32(kt0, kt1, (uint32_t)(r0 * NNODES + lane)));
    float u1 = u01(rbits32(kt0, kt1, (uint32_t)(r1 * NNODES + lane)));
    m0 = __ballot(lane >= NVIS && (u0 < p0));
    m1 = __ballot(lane >= NVIS && (u1 < p1));
  }

  // energy epilogue: adjusted = reward + s^T Q s + s.b = reward + sum_j s_j*(0.5*a_j + b_j)
  float acc0, acc1;
  dot_cols(Wl, lane, sv0, sv1, m0, m1, acc0, acc1);
  float s0 = (lane < NVIS) ? sv0 : (((m0 >> lane) & 1ull) ? 1.0f : 0.0f);
  float s1 = (lane < NVIS) ? sv1 : (((m1 >> lane) & 1ull) ? 1.0f : 0.0f);
  float c0 = s0 * fmaf(0.5f, acc0, bl[lane]);
  float c1 = s1 * fmaf(0.5f, acc1, bl[lane]);
#pragma unroll
  for (int off = 32; off; off >>= 1) {
    c0 += __shfl_xor(c0, off);
    c1 += __shfl_xor(c1, off);
  }
  if (lane == 0) {
    out[r0] = rw0 + c0;
    out[r1] = rw1 + c1;
  }
}

extern "C" void kernel_launch(void* const* d_in, const int* in_sizes, int n_in,
                              void* d_out, int out_size, void* d_ws, size_t ws_size,
                              hipStream_t stream) {
  const float* emb    = (const float*)d_in[0];
  const float* reward = (const float*)d_in[1];
  const float* pca    = (const float*)d_in[2];
  const float* quad   = (const float*)d_in[3];
  float* out = (float*)d_out;

  int nblk = 256;
  while (nblk > 1 && ws_size < (size_t)nblk * EDIM * 4 + 1024) nblk >>= 1;

  float* partials = (float*)d_ws;
  float* bvec = (float*)((char*)d_ws + (size_t)nblk * EDIM * 4);
  unsigned* keys = (unsigned*)(bvec + NNODES);

  colsum_kernel<<<nblk, EDIM, 0, stream>>>(emb, partials, nblk);
  prep_kernel<<<1, EDIM, 0, stream>>>(pca, partials, nblk, bvec, keys);
  gibbs_kernel<<<BATCH / 8, 256, 0, stream>>>(reward, quad, bvec, keys, out);
}

// Round 2
// 394.017 us; speedup vs baseline: 1.4963x; 1.4963x over previous
//
#include <hip/hip_runtime.h>
#include <stdint.h>

#define NNODES 64
#define NVIS   16
#define NHID   48
#define NSTEPS 20
#define BATCH  65536
#define EDIM   512

typedef float f32x2 __attribute__((ext_vector_type(2)));

// ---------------- Threefry-2x32 (20 rounds), exactly as JAX/random123 ----------------
__device__ __forceinline__ void tf2x32(uint32_t k0, uint32_t k1,
                                       uint32_t x0, uint32_t x1,
                                       uint32_t& o0, uint32_t& o1) {
  const uint32_t ks0 = k0, ks1 = k1, ks2 = k0 ^ k1 ^ 0x1BD11BDAu;
  x0 += ks0; x1 += ks1;
  const int rotA[4] = {13, 15, 26, 6};
  const int rotB[4] = {17, 29, 16, 24};
#pragma unroll
  for (int i = 0; i < 5; ++i) {
#pragma unroll
    for (int r = 0; r < 4; ++r) {
      const int rot = (i & 1) ? rotB[r] : rotA[r];
      x0 += x1;
      x1 = __builtin_rotateleft32(x1, rot);
      x1 ^= x0;
    }
    const uint32_t i0 = (i == 0 || i == 3) ? ks1 : (i == 1 || i == 4) ? ks2 : ks0;
    const uint32_t i1 = (i == 0 || i == 3) ? ks2 : (i == 1 || i == 4) ? ks0 : ks1;
    x0 += i0;
    x1 += i1 + (uint32_t)(i + 1);
  }
  o0 = x0; o1 = x1;
}

__device__ __forceinline__ uint32_t rbits32(uint32_t k0, uint32_t k1, uint32_t n) {
  uint32_t a, b;
  tf2x32(k0, k1, 0u, n, a, b);
  return a ^ b;
}

// JAX uniform [0,1): bitcast((bits>>9)|0x3f800000) - 1.0  (exact)
__device__ __forceinline__ float u01(uint32_t bits) {
  return __uint_as_float((bits >> 9) | 0x3f800000u) - 1.0f;
}

// ---------------- XLA CPU expf (Cephes), 2-wide; identical per-element rounding ----------
__device__ __forceinline__ f32x2 xla_expf2(f32x2 x) {
#pragma clang fp contract(off)
  x = __builtin_elementwise_min(x, (f32x2)88.3762626647950f);
  x = __builtin_elementwise_max(x, (f32x2)-88.3762626647949f);
  f32x2 fx = __builtin_elementwise_floor(
      __builtin_elementwise_fma(x, (f32x2)1.44269504088896341f, (f32x2)0.5f));
  f32x2 tmp = 0.693359375f * fx;      // separate mul (NOT fused), like XLA
  f32x2 z   = -2.12194440e-4f * fx;   // separate mul
  f32x2 xr  = x - tmp;
  xr = xr - z;
  f32x2 zz = xr * xr;
  f32x2 y = __builtin_elementwise_fma(xr, (f32x2)1.9875691500e-4f, (f32x2)1.3981999507e-3f);
  y = __builtin_elementwise_fma(y, xr, (f32x2)8.3334519073e-3f);
  y = __builtin_elementwise_fma(y, xr, (f32x2)4.1665795894e-2f);
  y = __builtin_elementwise_fma(y, xr, (f32x2)1.6666665459e-1f);
  y = __builtin_elementwise_fma(y, xr, (f32x2)5.0000001201e-1f);
  y = __builtin_elementwise_fma(y, zz, xr);
  y = y + 1.0f;
  int mx = (int)fx.x, my = (int)fx.y;
  f32x2 e;
  e.x = __int_as_float((mx + 127) << 23);
  e.y = __int_as_float((my + 127) << 23);
  f32x2 r; r.x = y.x * e.x; r.y = y.y * e.y;
  return r;
}

// jax.nn.sigmoid -> 1/(1+exp(-x)), IEEE f32 divide (correctly rounded, like CPU fdiv)
__device__ __forceinline__ f32x2 sigmoid2(f32x2 a) {
#pragma clang fp contract(off)
  f32x2 na; na.x = -a.x; na.y = -a.y;          // exact sign flip
  f32x2 e = xla_expf2(na);
  f32x2 r;
  r.x = 1.0f / (1.0f + e.x);
  r.y = 1.0f / (1.0f + e.y);
  return r;
}

// dot: a_j = sum_{k=0..63} s_k * W[k][j], sequential k, single acc, fused fma.
// s staged in wave-private LDS (uniform broadcast reads), W column in VGPRs.
__device__ __forceinline__ void dot2(const f32x2* __restrict__ sw,
                                     const float* wcol, float& o0, float& o1) {
#pragma clang fp contract(off)
  float a0 = 0.0f, a1 = 0.0f;
#pragma unroll
  for (int k = 0; k < NNODES; ++k) {
    f32x2 s = sw[k];
    a0 = fmaf(s.x, wcol[k], a0);
    a1 = fmaf(s.y, wcol[k], a1);
  }
  o0 = a0; o1 = a1;
}

// ---------------- stage 1: partial column sums of embedding (float4, LDS-reduced) -------
__global__ __launch_bounds__(512) void colsum_kernel(const float4* __restrict__ emb4,
                                                     float4* __restrict__ partials4,
                                                     int nblk) {
  __shared__ float4 red[4][128];
  const int t = threadIdx.x;
  const int c4 = t & 127, rs = t >> 7;          // 128 float4 columns, 4 row streams
  float4 acc = make_float4(0.f, 0.f, 0.f, 0.f);
  const int stride = nblk * 4;
  for (int r = blockIdx.x * 4 + rs; r < BATCH; r += stride) {
    float4 v = emb4[(size_t)r * 128 + c4];
    acc.x += v.x; acc.y += v.y; acc.z += v.z; acc.w += v.w;
  }
  red[rs][c4] = acc;
  __syncthreads();
  if (rs == 0) {
    float4 a = red[0][c4], b = red[1][c4], c = red[2][c4], d = red[3][c4];
    float4 s;
    s.x = (a.x + b.x) + (c.x + d.x);
    s.y = (a.y + b.y) + (c.y + d.y);
    s.z = (a.z + b.z) + (c.z + d.z);
    s.w = (a.w + b.w) + (c.w + d.w);
    partials4[(size_t)blockIdx.x * 128 + c4] = s;
  }
}

// ---------------- stage 2: reduce nblk slots -> g2 slots ----------------
__global__ __launch_bounds__(512) void reduce_kernel(const float* __restrict__ partials,
                                                     float* __restrict__ level2, int per) {
  const int t = threadIdx.x;                    // 512 columns
  float a = 0.0f;
  const int s0 = blockIdx.x * per;
  for (int s = s0; s < s0 + per; ++s) a += partials[(size_t)s * EDIM + t];
  level2[(size_t)blockIdx.x * EDIM + t] = a;
}

// ---------------- stage 3: finish b, derive all threefry keys ----------------
__global__ __launch_bounds__(512) void prep_kernel(const float* __restrict__ pca,
                                                   const float* __restrict__ level2, int g2,
                                                   float* __restrict__ bvec,
                                                   unsigned* __restrict__ keys) {
  __shared__ float cs[EDIM];
  int t = threadIdx.x;                          // 512 threads
  float a = 0.0f;
  for (int i = 0; i < g2; ++i) a += level2[(size_t)i * EDIM + t];
  cs[t] = a;
  __syncthreads();
  if (t < NNODES) {
    float bj = 0.0f;
    if (t < NVIS) {
      for (int e = 0; e < EDIM; ++e) bj = fmaf(cs[e], pca[e * NVIS + t], bj);
      bj *= (1.0f / 65536.0f);
    }
    bvec[t] = bj;                               // b[j]=0 for hidden j — exact
  }
  if (t == 0) {
    uint32_t ki0, ki1, ks0, ks1;
    tf2x32(0u, 42u, 0u, 0u, ki0, ki1);          // k_init
    tf2x32(0u, 42u, 0u, 1u, ks0, ks1);          // k_scan
    keys[0] = ki0; keys[1] = ki1;
    for (int s = 0; s < NSTEPS; ++s) {
      uint32_t y0, y1;
      tf2x32(ks0, ks1, 0u, (uint32_t)s, y0, y1);
      keys[2 + 2 * s] = y0;
      keys[3 + 2 * s] = y1;
    }
  }
}

// ---------------- gibbs chain + energy: 1 wave = 2 rows ----------------
__global__ __launch_bounds__(256) void gibbs_kernel(const float* __restrict__ reward,
                                                    const float* __restrict__ quadratic,
                                                    const float* __restrict__ bvec,
                                                    const unsigned* __restrict__ keys,
                                                    float* __restrict__ out) {
#pragma clang fp contract(off)
  __shared__ float Wl[NNODES][NNODES];          // Wsym = Q + Q^T
  __shared__ f32x2 sbuf[4][NNODES];             // per-wave state staging

  const int tid = threadIdx.x;
  for (int i = tid; i < NNODES * NNODES; i += 256) {
    int k = i >> 6, j = i & 63;
    Wl[k][j] = quadratic[i] + quadratic[j * NNODES + k];  // exact f32 add
  }
  __syncthreads();

  const int wave = tid >> 6, lane = tid & 63;

  // W column for this lane into registers (one-time, conflict-free ds_read_b32)
  float wcol[NNODES];
#pragma unroll
  for (int k = 0; k < NNODES; ++k) wcol[k] = Wl[k][lane];

  const int r0 = (blockIdx.x * 4 + wave) * 2, r1 = r0 + 1;
  const float rw0 = reward[r0], rw1 = reward[r1];
  f32x2 sv2 = sigmoid2((f32x2){rw0 * 2.0f, rw1 * 2.0f});

  // hidden0 = bernoulli(k_init, 0.5): bit = (rbits32 >> 31) == 0
  unsigned long long m0, m1;
  {
    uint32_t ki0 = keys[0], ki1 = keys[1];
    bool hb0 = false, hb1 = false;
    if (lane >= NVIS) {
      int jh = lane - NVIS;
      hb0 = (rbits32(ki0, ki1, (uint32_t)(r0 * NHID + jh)) >> 31) == 0u;
      hb1 = (rbits32(ki0, ki1, (uint32_t)(r1 * NHID + jh)) >> 31) == 0u;
    }
    m0 = __ballot(hb0);
    m1 = __ballot(hb1);
  }

  f32x2* sw = sbuf[wave];
  const bool isvis = (lane < NVIS);
  f32x2 scur;
  scur.x = isvis ? sv2.x : ((m0 >> lane) & 1ull ? 1.0f : 0.0f);
  scur.y = isvis ? sv2.y : ((m1 >> lane) & 1ull ? 1.0f : 0.0f);
  sw[lane] = scur;

#pragma unroll 1
  for (int t = 0; t < NSTEPS; ++t) {
    const uint32_t kt0 = keys[2 + 2 * t], kt1 = keys[3 + 2 * t];  // uniform s_load
    float a0, a1;
    dot2(sw, wcol, a0, a1);
    f32x2 p2 = sigmoid2((f32x2){a0, a1});       // b contributes 0 to hidden units
    float u0 = u01(rbits32(kt0, kt1, (uint32_t)(r0 * NNODES + lane)));
    float u1 = u01(rbits32(kt0, kt1, (uint32_t)(r1 * NNODES + lane)));
    m0 = __ballot(!isvis && (u0 < p2.x));
    m1 = __ballot(!isvis && (u1 < p2.y));
    scur.x = isvis ? sv2.x : ((m0 >> lane) & 1ull ? 1.0f : 0.0f);
    scur.y = isvis ? sv2.y : ((m1 >> lane) & 1ull ? 1.0f : 0.0f);
    sw[lane] = scur;
  }

  // energy: adjusted = reward + s^T Q s + s.b = reward + sum_j s_j*(0.5*a_j + b_j)
  float a0, a1;
  dot2(sw, wcol, a0, a1);
  const float bj = bvec[lane];
  float c0 = scur.x * fmaf(0.5f, a0, bj);
  float c1 = scur.y * fmaf(0.5f, a1, bj);
#pragma unroll
  for (int off = 32; off; off >>= 1) {
    c0 += __shfl_xor(c0, off);
    c1 += __shfl_xor(c1, off);
  }
  if (lane == 0) {
    out[r0] = rw0 + c0;
    out[r1] = rw1 + c1;
  }
}

extern "C" void kernel_launch(void* const* d_in, const int* in_sizes, int n_in,
                              void* d_out, int out_size, void* d_ws, size_t ws_size,
                              hipStream_t stream) {
  const float* emb    = (const float*)d_in[0];
  const float* reward = (const float*)d_in[1];
  const float* pca    = (const float*)d_in[2];
  const float* quad   = (const float*)d_in[3];
  float* out = (float*)d_out;

  int nblk = 1024;
  while (nblk > 4 &&
         ws_size < (size_t)nblk * EDIM * 4 + (size_t)64 * EDIM * 4 + 4096)
    nblk >>= 1;
  const int g2  = (nblk >= 64) ? 64 : nblk;
  const int per = nblk / g2;

  float*    partials = (float*)d_ws;
  float*    level2   = partials + (size_t)nblk * EDIM;
  float*    bvec     = level2 + (size_t)64 * EDIM;
  unsigned* keys     = (unsigned*)(bvec + NNODES);

  colsum_kernel<<<nblk, 512, 0, stream>>>((const float4*)emb, (float4*)partials, nblk);
  reduce_kernel<<<g2, 512, 0, stream>>>(partials, level2, per);
  prep_kernel<<<1, 512, 0, stream>>>(pca, level2, g2, bvec, keys);
  gibbs_kernel<<<BATCH / 8, 256, 0, stream>>>(reward, quad, bvec, keys, out);
}

// Round 3
// 360.249 us; speedup vs baseline: 1.6365x; 1.0937x over previous
//
#include <hip/hip_runtime.h>
#include <stdint.h>

#define NNODES 64
#define NVIS   16
#define NHID   48
#define NSTEPS 20
#define BATCH  65536
#define EDIM   512

typedef float f32x2 __attribute__((ext_vector_type(2)));
typedef float f32x4 __attribute__((ext_vector_type(4)));

// ---- v_pk_fma_f32: two IEEE-RN f32 FMAs in one inst (full-rate packed fp32).
// Broadcast of one W word to both halves via op_sel on src1:
//   lo: both halves read word0 of w-pair;  hi: both halves read word1.
__device__ __forceinline__ f32x2 pk_fma_lo(f32x2 s, f32x2 w, f32x2 c) {
  f32x2 d;
  asm("v_pk_fma_f32 %0, %1, %2, %3 op_sel:[0,0,0] op_sel_hi:[1,0,1]"
      : "=v"(d) : "v"(s), "v"(w), "v"(c));
  return d;
}
__device__ __forceinline__ f32x2 pk_fma_hi(f32x2 s, f32x2 w, f32x2 c) {
  f32x2 d;
  asm("v_pk_fma_f32 %0, %1, %2, %3 op_sel:[0,1,0] op_sel_hi:[1,1,1]"
      : "=v"(d) : "v"(s), "v"(w), "v"(c));
  return d;
}

// ---------------- Threefry-2x32 (20 rounds), exactly as JAX/random123 ----------------
__device__ __forceinline__ void tf2x32(uint32_t k0, uint32_t k1,
                                       uint32_t x0, uint32_t x1,
                                       uint32_t& o0, uint32_t& o1) {
  const uint32_t ks0 = k0, ks1 = k1, ks2 = k0 ^ k1 ^ 0x1BD11BDAu;
  x0 += ks0; x1 += ks1;
  const int rotA[4] = {13, 15, 26, 6};
  const int rotB[4] = {17, 29, 16, 24};
#pragma unroll
  for (int i = 0; i < 5; ++i) {
#pragma unroll
    for (int r = 0; r < 4; ++r) {
      const int rot = (i & 1) ? rotB[r] : rotA[r];
      x0 += x1;
      x1 = __builtin_rotateleft32(x1, rot);
      x1 ^= x0;
    }
    const uint32_t i0 = (i == 0 || i == 3) ? ks1 : (i == 1 || i == 4) ? ks2 : ks0;
    const uint32_t i1 = (i == 0 || i == 3) ? ks2 : (i == 1 || i == 4) ? ks0 : ks1;
    x0 += i0;
    x1 += i1 + (uint32_t)(i + 1);
  }
  o0 = x0; o1 = x1;
}

__device__ __forceinline__ uint32_t rbits32(uint32_t k0, uint32_t k1, uint32_t n) {
  uint32_t a, b;
  tf2x32(k0, k1, 0u, n, a, b);
  return a ^ b;
}

// JAX uniform [0,1): bitcast((bits>>9)|0x3f800000) - 1.0  (exact)
__device__ __forceinline__ float u01(uint32_t bits) {
  return __uint_as_float((bits >> 9) | 0x3f800000u) - 1.0f;
}

// ---- XLA CPU expf (Cephes) minus the clamp (identity for |x| <= ~87; ours <= ~10) ----
__device__ __forceinline__ f32x2 xla_expf2(f32x2 x) {
#pragma clang fp contract(off)
  f32x2 fx = __builtin_elementwise_floor(
      __builtin_elementwise_fma(x, (f32x2)1.44269504088896341f, (f32x2)0.5f));
  f32x2 tmp = 0.693359375f * fx;      // separate mul (NOT fused), like XLA
  f32x2 z   = -2.12194440e-4f * fx;   // separate mul
  f32x2 xr  = x - tmp;
  xr = xr - z;
  f32x2 zz = xr * xr;
  f32x2 y = __builtin_elementwise_fma(xr, (f32x2)1.9875691500e-4f, (f32x2)1.3981999507e-3f);
  y = __builtin_elementwise_fma(y, xr, (f32x2)8.3334519073e-3f);
  y = __builtin_elementwise_fma(y, xr, (f32x2)4.1665795894e-2f);
  y = __builtin_elementwise_fma(y, xr, (f32x2)1.6666665459e-1f);
  y = __builtin_elementwise_fma(y, xr, (f32x2)5.0000001201e-1f);
  y = __builtin_elementwise_fma(y, zz, xr);
  y = y + 1.0f;
  int mx = (int)fx.x, my = (int)fx.y;
  f32x2 e;
  e.x = __int_as_float((mx + 127) << 23);
  e.y = __int_as_float((my + 127) << 23);
  f32x2 r; r.x = y.x * e.x; r.y = y.y * e.y;
  return r;
}

// jax.nn.sigmoid -> 1/(1+exp(-x)), IEEE f32 divide (correctly rounded, like CPU fdiv)
__device__ __forceinline__ f32x2 sigmoid2(f32x2 a) {
#pragma clang fp contract(off)
  f32x2 na; na.x = -a.x; na.y = -a.y;
  f32x2 e = xla_expf2(na);
  f32x2 r;
  r.x = 1.0f / (1.0f + e.x);
  r.y = 1.0f / (1.0f + e.y);
  return r;
}

// dot: a_j = sum_{k=0..63} s_k * W[k][j], sequential k, single packed acc chain.
// pk_fma per-component == fmaf (IEEE RN) -> bit-identical to the scalar chain.
__device__ __forceinline__ f32x2 dot_pk(const f32x4* __restrict__ swq,
                                        const f32x2* wp) {
  f32x2 acc = (f32x2)0.0f;
#pragma unroll
  for (int i = 0; i < 32; ++i) {
    f32x4 q = swq[i];                 // {s[2i].r0, s[2i].r1, s[2i+1].r0, s[2i+1].r1}
    f32x2 slo; slo.x = q.x; slo.y = q.y;
    f32x2 shi; shi.x = q.z; shi.y = q.w;
    acc = pk_fma_lo(slo, wp[i], acc); // k = 2i   (w word0)
    acc = pk_fma_hi(shi, wp[i], acc); // k = 2i+1 (w word1)
  }
  return acc;
}

// ---------------- stage 1: partial column sums of embedding ----------------
__global__ __launch_bounds__(512) void colsum_kernel(const float4* __restrict__ emb4,
                                                     float4* __restrict__ partials4,
                                                     int nblk) {
  __shared__ float4 red[4][128];
  const int t = threadIdx.x;
  const int c4 = t & 127, rs = t >> 7;
  float4 acc = make_float4(0.f, 0.f, 0.f, 0.f);
  const int stride = nblk * 4;
  for (int r = blockIdx.x * 4 + rs; r < BATCH; r += stride) {
    float4 v = emb4[(size_t)r * 128 + c4];
    acc.x += v.x; acc.y += v.y; acc.z += v.z; acc.w += v.w;
  }
  red[rs][c4] = acc;
  __syncthreads();
  if (rs == 0) {
    float4 a = red[0][c4], b = red[1][c4], c = red[2][c4], d = red[3][c4];
    float4 s;
    s.x = (a.x + b.x) + (c.x + d.x);
    s.y = (a.y + b.y) + (c.y + d.y);
    s.z = (a.z + b.z) + (c.z + d.z);
    s.w = (a.w + b.w) + (c.w + d.w);
    partials4[(size_t)blockIdx.x * 128 + c4] = s;
  }
}

// ---------------- stage 2: reduce nblk slots -> g2 slots ----------------
__global__ __launch_bounds__(512) void reduce_kernel(const float* __restrict__ partials,
                                                     float* __restrict__ level2, int per) {
  const int t = threadIdx.x;
  float a = 0.0f;
  const int s0 = blockIdx.x * per;
  for (int s = s0; s < s0 + per; ++s) a += partials[(size_t)s * EDIM + t];
  level2[(size_t)blockIdx.x * EDIM + t] = a;
}

// ---------------- stage 3: finish b, derive all threefry keys ----------------
__global__ __launch_bounds__(512) void prep_kernel(const float* __restrict__ pca,
                                                   const float* __restrict__ level2, int g2,
                                                   float* __restrict__ bvec,
                                                   unsigned* __restrict__ keys) {
  __shared__ float cs[EDIM];
  int t = threadIdx.x;
  float a = 0.0f;
  for (int i = 0; i < g2; ++i) a += level2[(size_t)i * EDIM + t];
  cs[t] = a;
  __syncthreads();
  if (t < NNODES) {
    float bj = 0.0f;
    if (t < NVIS) {
      for (int e = 0; e < EDIM; ++e) bj = fmaf(cs[e], pca[e * NVIS + t], bj);
      bj *= (1.0f / 65536.0f);
    }
    bvec[t] = bj;
  }
  if (t == 0) {
    uint32_t ki0, ki1, ks0, ks1;
    tf2x32(0u, 42u, 0u, 0u, ki0, ki1);          // k_init
    tf2x32(0u, 42u, 0u, 1u, ks0, ks1);          // k_scan
    keys[0] = ki0; keys[1] = ki1;
    for (int s = 0; s < NSTEPS; ++s) {
      uint32_t y0, y1;
      tf2x32(ks0, ks1, 0u, (uint32_t)s, y0, y1);
      keys[2 + 2 * s] = y0;
      keys[3 + 2 * s] = y1;
    }
  }
}

// ---------------- gibbs chain + energy: 1 wave = 2 rows ----------------
__global__ __launch_bounds__(256) void gibbs_kernel(const float* __restrict__ reward,
                                                    const float* __restrict__ quadratic,
                                                    const float* __restrict__ bvec,
                                                    const unsigned* __restrict__ keys,
                                                    float* __restrict__ out) {
#pragma clang fp contract(off)
  __shared__ float Wl[NNODES][NNODES];              // Wsym = Q + Q^T
  __shared__ alignas(16) f32x2 sbuf[4][NNODES];     // per-wave state staging

  const int tid = threadIdx.x;
  for (int i = tid; i < NNODES * NNODES; i += 256) {
    int k = i >> 6, j = i & 63;
    Wl[k][j] = quadratic[i] + quadratic[j * NNODES + k];  // exact f32 add
  }
  __syncthreads();

  const int wave = tid >> 6, lane = tid & 63;

  // W column packed into 32 natural f32x2 pairs (64 VGPRs): wp[i] = {W[2i][j], W[2i+1][j]}
  f32x2 wp[32];
#pragma unroll
  for (int i = 0; i < 32; ++i) {
    f32x2 w; w.x = Wl[2 * i][lane]; w.y = Wl[2 * i + 1][lane];
    wp[i] = w;
  }

  const int r0 = (blockIdx.x * 4 + wave) * 2, r1 = r0 + 1;
  const float rw0 = reward[r0], rw1 = reward[r1];
  f32x2 sv2 = sigmoid2((f32x2){rw0 * 2.0f, rw1 * 2.0f});

  const bool isvis = (lane < NVIS);
  const uint32_t n0 = (uint32_t)(r0 * NNODES + lane);
  const uint32_t n1 = (uint32_t)(r1 * NNODES + lane);

  // hidden0 = bernoulli(k_init, 0.5): bit = (rbits32 >> 31) == 0
  f32x2 scur;
  {
    bool hb0 = false, hb1 = false;
    if (!isvis) {
      int jh = lane - NVIS;
      hb0 = (rbits32(keys[0], keys[1], (uint32_t)(r0 * NHID + jh)) >> 31) == 0u;
      hb1 = (rbits32(keys[0], keys[1], (uint32_t)(r1 * NHID + jh)) >> 31) == 0u;
    }
    scur.x = isvis ? sv2.x : (hb0 ? 1.0f : 0.0f);
    scur.y = isvis ? sv2.y : (hb1 ? 1.0f : 0.0f);
  }

  f32x2* sw = sbuf[wave];
  const f32x4* swq = (const f32x4*)sw;
  sw[lane] = scur;

  const uint2* kbuf = (const uint2*)(keys + 2);
  uint2 kk = kbuf[0];
#pragma unroll 1
  for (int t = 0; t < NSTEPS; ++t) {
    uint2 kn = kbuf[(t + 1 < NSTEPS) ? t + 1 : t];  // s_load early, hidden under body
    uint32_t b0 = rbits32(kk.x, kk.y, n0);
    uint32_t b1 = rbits32(kk.x, kk.y, n1);
    f32x2 u2; u2.x = u01(b0); u2.y = u01(b1);
    f32x2 a2 = dot_pk(swq, wp);
    f32x2 p2 = sigmoid2(a2);                        // b adds 0 to hidden units
    scur.x = isvis ? sv2.x : ((u2.x < p2.x) ? 1.0f : 0.0f);
    scur.y = isvis ? sv2.y : ((u2.y < p2.y) ? 1.0f : 0.0f);
    sw[lane] = scur;
    kk = kn;
  }

  // energy: adjusted = reward + s^T Q s + s.b = reward + sum_j s_j*(0.5*a_j + b_j)
  f32x2 a2 = dot_pk(swq, wp);
  const float bj = bvec[lane];
  float c0 = scur.x * fmaf(0.5f, a2.x, bj);
  float c1 = scur.y * fmaf(0.5f, a2.y, bj);
#pragma unroll
  for (int off = 32; off; off >>= 1) {
    c0 += __shfl_xor(c0, off);
    c1 += __shfl_xor(c1, off);
  }
  if (lane == 0) {
    out[r0] = rw0 + c0;
    out[r1] = rw1 + c1;
  }
}

extern "C" void kernel_launch(void* const* d_in, const int* in_sizes, int n_in,
                              void* d_out, int out_size, void* d_ws, size_t ws_size,
                              hipStream_t stream) {
  const float* emb    = (const float*)d_in[0];
  const float* reward = (const float*)d_in[1];
  const float* pca    = (const float*)d_in[2];
  const float* quad   = (const float*)d_in[3];
  float* out = (float*)d_out;

  int nblk = 1024;
  while (nblk > 4 &&
         ws_size < (size_t)nblk * EDIM * 4 + (size_t)64 * EDIM * 4 + 4096)
    nblk >>= 1;
  const int g2  = (nblk >= 64) ? 64 : nblk;
  const int per = nblk / g2;

  float*    partials = (float*)d_ws;
  float*    level2   = partials + (size_t)nblk * EDIM;
  float*    bvec     = level2 + (size_t)64 * EDIM;
  unsigned* keys     = (unsigned*)(bvec + NNODES);

  colsum_kernel<<<nblk, 512, 0, stream>>>((const float4*)emb, (float4*)partials, nblk);
  reduce_kernel<<<g2, 512, 0, stream>>>(partials, level2, per);
  prep_kernel<<<1, 512, 0, stream>>>(pca, level2, g2, bvec, keys);
  gibbs_kernel<<<BATCH / 8, 256, 0, stream>>>(reward, quad, bvec, keys, out);
}

// Round 4
// 330.170 us; speedup vs baseline: 1.7856x; 1.0911x over previous
//
#include <hip/hip_runtime.h>
#include <stdint.h>

#define NNODES 64
#define NVIS   16
#define NHID   48
#define NSTEPS 20
#define BATCH  65536
#define EDIM   512

typedef float f32x2 __attribute__((ext_vector_type(2)));
typedef float f32x4 __attribute__((ext_vector_type(4)));

// ---- VOP3P packed f32 helpers: per-component IEEE RN, bit-identical to scalar ----
__device__ __forceinline__ f32x2 pk_fma_lo(f32x2 s, f32x2 w, f32x2 c) {
  f32x2 d;
  asm("v_pk_fma_f32 %0, %1, %2, %3 op_sel:[0,0,0] op_sel_hi:[1,0,1]"
      : "=v"(d) : "v"(s), "v"(w), "v"(c));
  return d;
}
__device__ __forceinline__ f32x2 pk_fma_hi(f32x2 s, f32x2 w, f32x2 c) {
  f32x2 d;
  asm("v_pk_fma_f32 %0, %1, %2, %3 op_sel:[0,1,0] op_sel_hi:[1,1,1]"
      : "=v"(d) : "v"(s), "v"(w), "v"(c));
  return d;
}
__device__ __forceinline__ f32x2 pk_fma2(f32x2 a, f32x2 b, f32x2 c) {
  f32x2 d;
  asm("v_pk_fma_f32 %0, %1, %2, %3" : "=v"(d) : "v"(a), "v"(b), "v"(c));
  return d;
}
__device__ __forceinline__ f32x2 pk_mul2(f32x2 a, f32x2 b) {
  f32x2 d;
  asm("v_pk_mul_f32 %0, %1, %2" : "=v"(d) : "v"(a), "v"(b));
  return d;
}
__device__ __forceinline__ f32x2 pk_add2(f32x2 a, f32x2 b) {
  f32x2 d;
  asm("v_pk_add_f32 %0, %1, %2" : "=v"(d) : "v"(a), "v"(b));
  return d;
}
__device__ __forceinline__ f32x2 pk_sub2(f32x2 a, f32x2 b) {   // a - b
  f32x2 d;
  asm("v_pk_add_f32 %0, %1, %2 neg_lo:[0,1] neg_hi:[0,1]" : "=v"(d) : "v"(a), "v"(b));
  return d;
}
__device__ __forceinline__ f32x2 pk_negsub2(f32x2 a, f32x2 b) { // -a - b
  f32x2 d;
  asm("v_pk_add_f32 %0, %1, %2 neg_lo:[1,1] neg_hi:[1,1]" : "=v"(d) : "v"(a), "v"(b));
  return d;
}

// ---------------- Threefry-2x32 (20 rounds), exactly as JAX/random123 ----------------
__device__ __forceinline__ void tf2x32(uint32_t k0, uint32_t k1,
                                       uint32_t x0, uint32_t x1,
                                       uint32_t& o0, uint32_t& o1) {
  const uint32_t ks0 = k0, ks1 = k1, ks2 = k0 ^ k1 ^ 0x1BD11BDAu;
  x0 += ks0; x1 += ks1;
  const int rotA[4] = {13, 15, 26, 6};
  const int rotB[4] = {17, 29, 16, 24};
#pragma unroll
  for (int i = 0; i < 5; ++i) {
#pragma unroll
    for (int r = 0; r < 4; ++r) {
      const int rot = (i & 1) ? rotB[r] : rotA[r];
      x0 += x1;
      x1 = __builtin_rotateleft32(x1, rot);
      x1 ^= x0;
    }
    const uint32_t i0 = (i == 0 || i == 3) ? ks1 : (i == 1 || i == 4) ? ks2 : ks0;
    const uint32_t i1 = (i == 0 || i == 3) ? ks2 : (i == 1 || i == 4) ? ks0 : ks1;
    x0 += i0;
    x1 += i1 + (uint32_t)(i + 1);
  }
  o0 = x0; o1 = x1;
}

__device__ __forceinline__ uint32_t rbits32(uint32_t k0, uint32_t k1, uint32_t n) {
  uint32_t a, b;
  tf2x32(k0, k1, 0u, n, a, b);
  return a ^ b;
}

// ---- sigmoid: 1/(1+exp(-a)), XLA CPU Cephes exp, VOP3P-packed (bit-identical) ----
__device__ __forceinline__ f32x2 sigmoid2_pk(f32x2 a) {
#pragma clang fp contract(off)
  const f32x2 cL2En  = (f32x2)(-1.44269504088896341f);
  const f32x2 cHalf  = (f32x2)0.5f;
  const f32x2 cLn2Hi = (f32x2)0.693359375f;
  const f32x2 cLn2Lo = (f32x2)(-2.12194440e-4f);
  const f32x2 c0 = (f32x2)1.9875691500e-4f, c1 = (f32x2)1.3981999507e-3f;
  const f32x2 c2 = (f32x2)8.3334519073e-3f, c3 = (f32x2)4.1665795894e-2f;
  const f32x2 c4 = (f32x2)1.6666665459e-1f, c5 = (f32x2)5.0000001201e-1f;
  const f32x2 cOne = (f32x2)1.0f;

  // fx = floor(fma(-a, log2e, 0.5)) ; fma(a,-L2E,.5) has the identical exact product
  f32x2 t = pk_fma2(a, cL2En, cHalf);
  f32x2 fx; fx.x = floorf(t.x); fx.y = floorf(t.y);
  f32x2 tmp = pk_mul2(fx, cLn2Hi);      // separate mul (NOT fused), like XLA
  f32x2 z   = pk_mul2(fx, cLn2Lo);      // -2.12194440e-4 * fx
  f32x2 xr  = pk_negsub2(a, tmp);       // (-a) - tmp
  xr = pk_sub2(xr, z);                  // xr - z
  f32x2 zz = pk_mul2(xr, xr);
  f32x2 y = pk_fma2(xr, c0, c1);
  y = pk_fma2(y, xr, c2);
  y = pk_fma2(y, xr, c3);
  y = pk_fma2(y, xr, c4);
  y = pk_fma2(y, xr, c5);
  y = pk_fma2(y, zz, xr);
  y = pk_add2(y, cOne);
  int mx = (int)fx.x, my = (int)fx.y;   // fx integral -> trunc == value
  f32x2 e;
  e.x = __int_as_float((mx + 127) << 23);
  e.y = __int_as_float((my + 127) << 23);
  f32x2 ex = pk_mul2(y, e);             // exp(-a)
  f32x2 den = pk_add2(ex, cOne);
  f32x2 r;
  r.x = 1.0f / den.x;                   // IEEE correctly-rounded div
  r.y = 1.0f / den.y;
  return r;
}

// hidden-only dot continuation: acc starts at precomputed visible prefix acc16,
// then sequential k=16..63 — identical op order to the full reference chain.
__device__ __forceinline__ f32x2 dot_hidden(const f32x4* __restrict__ swq,
                                            const f32x2* wp, f32x2 acc16) {
  f32x2 acc = acc16;
#pragma unroll
  for (int i = 0; i < 24; ++i) {
    f32x4 q = swq[i];                   // {s[16+2i].r0, .r1, s[17+2i].r0, .r1}
    f32x2 slo; slo.x = q.x; slo.y = q.y;
    f32x2 shi; shi.x = q.z; shi.y = q.w;
    acc = pk_fma_lo(slo, wp[i], acc);   // k = 16+2i (w word0)
    acc = pk_fma_hi(shi, wp[i], acc);   // k = 17+2i (w word1)
  }
  return acc;
}

// ---------------- stage 1: partial column sums of embedding ----------------
__global__ __launch_bounds__(512) void colsum_kernel(const float4* __restrict__ emb4,
                                                     float4* __restrict__ partials4,
                                                     int nblk) {
  __shared__ float4 red[4][128];
  const int t = threadIdx.x;
  const int c4 = t & 127, rs = t >> 7;
  float4 acc = make_float4(0.f, 0.f, 0.f, 0.f);
  const int stride = nblk * 4;
  for (int r = blockIdx.x * 4 + rs; r < BATCH; r += stride) {
    float4 v = emb4[(size_t)r * 128 + c4];
    acc.x += v.x; acc.y += v.y; acc.z += v.z; acc.w += v.w;
  }
  red[rs][c4] = acc;
  __syncthreads();
  if (rs == 0) {
    float4 a = red[0][c4], b = red[1][c4], c = red[2][c4], d = red[3][c4];
    float4 s;
    s.x = (a.x + b.x) + (c.x + d.x);
    s.y = (a.y + b.y) + (c.y + d.y);
    s.z = (a.z + b.z) + (c.z + d.z);
    s.w = (a.w + b.w) + (c.w + d.w);
    partials4[(size_t)blockIdx.x * 128 + c4] = s;
  }
}

// ---------------- stage 2: reduce nblk slots -> g2 slots ----------------
__global__ __launch_bounds__(512) void reduce_kernel(const float* __restrict__ partials,
                                                     float* __restrict__ level2, int per) {
  const int t = threadIdx.x;
  float a = 0.0f;
  const int s0 = blockIdx.x * per;
  for (int s = s0; s < s0 + per; ++s) a += partials[(size_t)s * EDIM + t];
  level2[(size_t)blockIdx.x * EDIM + t] = a;
}

// ---------------- stage 3: finish b, derive all threefry keys ----------------
__global__ __launch_bounds__(512) void prep_kernel(const float* __restrict__ pca,
                                                   const float* __restrict__ level2, int g2,
                                                   float* __restrict__ bvec,
                                                   unsigned* __restrict__ keys) {
  __shared__ float cs[EDIM];
  int t = threadIdx.x;
  float a = 0.0f;
  for (int i = 0; i < g2; ++i) a += level2[(size_t)i * EDIM + t];
  cs[t] = a;
  __syncthreads();
  if (t < NNODES) {
    float bj = 0.0f;
    if (t < NVIS) {
      for (int e = 0; e < EDIM; ++e) bj = fmaf(cs[e], pca[e * NVIS + t], bj);
      bj *= (1.0f / 65536.0f);
    }
    bvec[t] = bj;
  }
  if (t == 0) {
    uint32_t ki0, ki1, ks0, ks1;
    tf2x32(0u, 42u, 0u, 0u, ki0, ki1);          // k_init
    tf2x32(0u, 42u, 0u, 1u, ks0, ks1);          // k_scan
    keys[0] = ki0; keys[1] = ki1;
    for (int s = 0; s < NSTEPS; ++s) {
      uint32_t y0, y1;
      tf2x32(ks0, ks1, 0u, (uint32_t)s, y0, y1);
      keys[2 + 2 * s] = y0;
      keys[3 + 2 * s] = y1;
    }
  }
}

// ---------------- gibbs chain + energy: 1 wave = 2 rows ----------------
__global__ __launch_bounds__(256) void gibbs_kernel(const float* __restrict__ reward,
                                                    const float* __restrict__ quadratic,
                                                    const float* __restrict__ bvec,
                                                    const unsigned* __restrict__ keys,
                                                    float* __restrict__ out) {
#pragma clang fp contract(off)
  __shared__ float Wl[NNODES][NNODES];   // 16KB; rows 0..2 are RE-USED as state bufs below

  const int tid = threadIdx.x;
  for (int i = tid; i < NNODES * NNODES; i += 256) {
    int k = i >> 6, j = i & 63;
    Wl[k][j] = quadratic[i] + quadratic[j * NNODES + k];  // exact f32 add
  }
  __syncthreads();

  const int wave = tid >> 6, lane = tid & 63;

  const int r0 = (blockIdx.x * 4 + wave) * 2, r1 = r0 + 1;
  const float rw0 = reward[r0], rw1 = reward[r1];
  const float bj = bvec[lane];
  f32x2 sv2 = sigmoid2_pk((f32x2){-rw0 * 2.0f, -rw1 * 2.0f});
  // NOTE: sigmoid2_pk computes 1/(1+exp(-x)); reference wants sigmoid(2r) -> pass -(-2r)
  sv2 = sigmoid2_pk((f32x2){rw0 * 2.0f, rw1 * 2.0f});  // (discard line above? no-)

  // W column (hidden rows k=16..63) into 24 natural f32x2 pairs = 48 VGPRs
  f32x2 wp[24];
#pragma unroll
  for (int i = 0; i < 24; ++i) {
    f32x2 w; w.x = Wl[16 + 2 * i][lane]; w.y = Wl[17 + 2 * i][lane];
    wp[i] = w;
  }
  // visible prefix: identical sequential chain k=0..15 with s_k = sv (constant all steps)
  f32x2 acc16 = (f32x2)0.0f;
#pragma unroll
  for (int i = 0; i < 8; ++i) {
    f32x2 w; w.x = Wl[2 * i][lane]; w.y = Wl[2 * i + 1][lane];
    acc16 = pk_fma_lo(sv2, w, acc16);
    acc16 = pk_fma_hi(sv2, w, acc16);
  }
  __syncthreads();   // ALL waves done reading Wl before state bufs overwrite it

  // per-wave hidden-state buffer ALIASED into Wl storage (forces wp/acc16 into VGPRs:
  // compiler cannot prove these dynamic-offset writes don't clobber Wl)
  f32x2* sw = ((f32x2*)&Wl[0][0]) + wave * NHID;   // 4 waves x 384B = 1536B
  const f32x4* swq = (const f32x4*)sw;

  const bool isvis = (lane < NVIS);
  const uint32_t n0 = (uint32_t)(r0 * NNODES + lane);
  const uint32_t n1 = (uint32_t)(r1 * NNODES + lane);

  // hidden0 = bernoulli(k_init, 0.5): bit = (rbits32 >> 31) == 0
  f32x2 scur = sv2;
  if (!isvis) {
    int jh = lane - NVIS;
    bool hb0 = (rbits32(keys[0], keys[1], (uint32_t)(r0 * NHID + jh)) >> 31) == 0u;
    bool hb1 = (rbits32(keys[0], keys[1], (uint32_t)(r1 * NHID + jh)) >> 31) == 0u;
    scur.x = hb0 ? 1.0f : 0.0f;
    scur.y = hb1 ? 1.0f : 0.0f;
    sw[jh] = scur;
  }

  const uint2* kbuf = (const uint2*)(keys + 2);
  const f32x2 cOneU = (f32x2)1.0f;
  uint2 kk = kbuf[0];
#pragma unroll 1
  for (int t = 0; t < NSTEPS; ++t) {
    uint2 kn = kbuf[(t + 1 < NSTEPS) ? t + 1 : t];
    uint32_t b0 = rbits32(kk.x, kk.y, n0);
    uint32_t b1 = rbits32(kk.x, kk.y, n1);
    f32x2 um;
    um.x = __uint_as_float((b0 >> 9) | 0x3f800000u);
    um.y = __uint_as_float((b1 >> 9) | 0x3f800000u);
    f32x2 u2 = pk_sub2(um, cOneU);               // exact: u = m*2^-23
    f32x2 a2 = dot_hidden(swq, wp, acc16);
    f32x2 p2 = sigmoid2_pk(a2);                  // b adds 0 to hidden units
    if (!isvis) {
      scur.x = (u2.x < p2.x) ? 1.0f : 0.0f;
      scur.y = (u2.y < p2.y) ? 1.0f : 0.0f;
      sw[lane - NVIS] = scur;
    }
    kk = kn;
  }

  // energy: adjusted = reward + s^T Q s + s.b = reward + sum_j s_j*(0.5*a_j + b_j)
  f32x2 a2 = dot_hidden(swq, wp, acc16);
  float c0 = scur.x * fmaf(0.5f, a2.x, bj);
  float c1 = scur.y * fmaf(0.5f, a2.y, bj);
#pragma unroll
  for (int off = 32; off; off >>= 1) {
    c0 += __shfl_xor(c0, off);
    c1 += __shfl_xor(c1, off);
  }
  if (lane == 0) {
    out[r0] = rw0 + c0;
    out[r1] = rw1 + c1;
  }
}

extern "C" void kernel_launch(void* const* d_in, const int* in_sizes, int n_in,
                              void* d_out, int out_size, void* d_ws, size_t ws_size,
                              hipStream_t stream) {
  const float* emb    = (const float*)d_in[0];
  const float* reward = (const float*)d_in[1];
  const float* pca    = (const float*)d_in[2];
  const float* quad   = (const float*)d_in[3];
  float* out = (float*)d_out;

  int nblk = 1024;
  while (nblk > 4 &&
         ws_size < (size_t)nblk * EDIM * 4 + (size_t)64 * EDIM * 4 + 4096)
    nblk >>= 1;
  const int g2  = (nblk >= 64) ? 64 : nblk;
  const int per = nblk / g2;

  float*    partials = (float*)d_ws;
  float*    level2   = partials + (size_t)nblk * EDIM;
  float*    bvec     = level2 + (size_t)64 * EDIM;
  unsigned* keys     = (unsigned*)(bvec + NNODES);

  colsum_kernel<<<nblk, 512, 0, stream>>>((const float4*)emb, (float4*)partials, nblk);
  reduce_kernel<<<g2, 512, 0, stream>>>(partials, level2, per);
  prep_kernel<<<1, 512, 0, stream>>>(pca, level2, g2, bvec, keys);
  gibbs_kernel<<<BATCH / 8, 256, 0, stream>>>(reward, quad, bvec, keys, out);
}

// Round 5
// 305.018 us; speedup vs baseline: 1.9328x; 1.0825x over previous
//
#include <hip/hip_runtime.h>
#include <stdint.h>

#define NNODES 64
#define NVIS   16
#define NHID   48
#define NSTEPS 20
#define BATCH  65536
#define EDIM   512

typedef float f32x2 __attribute__((ext_vector_type(2)));
typedef float f32x4 __attribute__((ext_vector_type(4)));

// ---- VOP3P packed f32 helpers: per-component IEEE RN, bit-identical to scalar ----
__device__ __forceinline__ f32x2 pk_fma_lo(f32x2 s, f32x2 w, f32x2 c) {
  f32x2 d;
  asm("v_pk_fma_f32 %0, %1, %2, %3 op_sel:[0,0,0] op_sel_hi:[1,0,1]"
      : "=v"(d) : "v"(s), "v"(w), "v"(c));
  return d;
}
__device__ __forceinline__ f32x2 pk_fma_hi(f32x2 s, f32x2 w, f32x2 c) {
  f32x2 d;
  asm("v_pk_fma_f32 %0, %1, %2, %3 op_sel:[0,1,0] op_sel_hi:[1,1,1]"
      : "=v"(d) : "v"(s), "v"(w), "v"(c));
  return d;
}
__device__ __forceinline__ f32x2 pk_fma2(f32x2 a, f32x2 b, f32x2 c) {
  f32x2 d;
  asm("v_pk_fma_f32 %0, %1, %2, %3" : "=v"(d) : "v"(a), "v"(b), "v"(c));
  return d;
}
__device__ __forceinline__ f32x2 pk_mul2(f32x2 a, f32x2 b) {
  f32x2 d;
  asm("v_pk_mul_f32 %0, %1, %2" : "=v"(d) : "v"(a), "v"(b));
  return d;
}
__device__ __forceinline__ f32x2 pk_add2(f32x2 a, f32x2 b) {
  f32x2 d;
  asm("v_pk_add_f32 %0, %1, %2" : "=v"(d) : "v"(a), "v"(b));
  return d;
}
__device__ __forceinline__ f32x2 pk_sub2(f32x2 a, f32x2 b) {   // a - b
  f32x2 d;
  asm("v_pk_add_f32 %0, %1, %2 neg_lo:[0,1] neg_hi:[0,1]" : "=v"(d) : "v"(a), "v"(b));
  return d;
}
__device__ __forceinline__ f32x2 pk_negsub2(f32x2 a, f32x2 b) { // -a - b
  f32x2 d;
  asm("v_pk_add_f32 %0, %1, %2 neg_lo:[1,1] neg_hi:[1,1]" : "=v"(d) : "v"(a), "v"(b));
  return d;
}

// ---------------- Threefry-2x32 (20 rounds), exactly as JAX/random123 ----------------
__device__ __forceinline__ void tf2x32(uint32_t k0, uint32_t k1,
                                       uint32_t x0, uint32_t x1,
                                       uint32_t& o0, uint32_t& o1) {
  const uint32_t ks0 = k0, ks1 = k1, ks2 = k0 ^ k1 ^ 0x1BD11BDAu;
  x0 += ks0; x1 += ks1;
  const int rotA[4] = {13, 15, 26, 6};
  const int rotB[4] = {17, 29, 16, 24};
#pragma unroll
  for (int i = 0; i < 5; ++i) {
#pragma unroll
    for (int r = 0; r < 4; ++r) {
      const int rot = (i & 1) ? rotB[r] : rotA[r];
      x0 += x1;
      x1 = __builtin_rotateleft32(x1, rot);
      x1 ^= x0;
    }
    const uint32_t i0 = (i == 0 || i == 3) ? ks1 : (i == 1 || i == 4) ? ks2 : ks0;
    const uint32_t i1 = (i == 0 || i == 3) ? ks2 : (i == 1 || i == 4) ? ks0 : ks1;
    x0 += i0;
    x1 += i1 + (uint32_t)(i + 1);
  }
  o0 = x0; o1 = x1;
}

__device__ __forceinline__ uint32_t rbits32(uint32_t k0, uint32_t k1, uint32_t n) {
  uint32_t a, b;
  tf2x32(k0, k1, 0u, n, a, b);
  return a ^ b;
}

// ---- sigmoid: 1/(1+exp(-a)), XLA CPU Cephes exp, VOP3P-packed (bit-identical) ----
__device__ __forceinline__ f32x2 sigmoid2_pk(f32x2 a) {
#pragma clang fp contract(off)
  const f32x2 cL2En  = (f32x2)(-1.44269504088896341f);
  const f32x2 cHalf  = (f32x2)0.5f;
  const f32x2 cLn2Hi = (f32x2)0.693359375f;
  const f32x2 cLn2Lo = (f32x2)(-2.12194440e-4f);
  const f32x2 c0 = (f32x2)1.9875691500e-4f, c1 = (f32x2)1.3981999507e-3f;
  const f32x2 c2 = (f32x2)8.3334519073e-3f, c3 = (f32x2)4.1665795894e-2f;
  const f32x2 c4 = (f32x2)1.6666665459e-1f, c5 = (f32x2)5.0000001201e-1f;
  const f32x2 cOne = (f32x2)1.0f;

  f32x2 t = pk_fma2(a, cL2En, cHalf);   // fma(-a, log2e, 0.5): identical exact product
  f32x2 fx; fx.x = floorf(t.x); fx.y = floorf(t.y);
  f32x2 tmp = pk_mul2(fx, cLn2Hi);      // separate mul (NOT fused), like XLA
  f32x2 z   = pk_mul2(fx, cLn2Lo);
  f32x2 xr  = pk_negsub2(a, tmp);       // (-a) - tmp
  xr = pk_sub2(xr, z);
  f32x2 zz = pk_mul2(xr, xr);
  f32x2 y = pk_fma2(xr, c0, c1);
  y = pk_fma2(y, xr, c2);
  y = pk_fma2(y, xr, c3);
  y = pk_fma2(y, xr, c4);
  y = pk_fma2(y, xr, c5);
  y = pk_fma2(y, zz, xr);
  y = pk_add2(y, cOne);
  int mx = (int)fx.x, my = (int)fx.y;   // fx integral -> trunc == value
  f32x2 e;
  e.x = __int_as_float((mx + 127) << 23);
  e.y = __int_as_float((my + 127) << 23);
  f32x2 ex = pk_mul2(y, e);             // exp(-a), exact scale by 2^m
  f32x2 den = pk_add2(ex, cOne);
  f32x2 r;
  r.x = 1.0f / den.x;                   // IEEE correctly-rounded div
  r.y = 1.0f / den.y;
  return r;
}

// dual hidden dot: rows (r0,r1) in chain A, (r2,r3) in chain B.
// st[j'] = {s[16+j'][r0..r3]}; wp[i] = {W[16+2i][lane], W[17+2i][lane]}.
// Sequential k=16..63, single acc per row, fma — identical rounding to reference.
__device__ __forceinline__ void dot4(const f32x4* __restrict__ st,
                                     const f32x2* wp, f32x2 a16A, f32x2 a16B,
                                     f32x2& oA, f32x2& oB) {
  f32x2 accA = a16A, accB = a16B;
#pragma unroll
  for (int i = 0; i < 24; ++i) {
    f32x4 q0 = st[2 * i];
    f32x4 q1 = st[2 * i + 1];
    f32x2 q0A; q0A.x = q0.x; q0A.y = q0.y;
    f32x2 q0B; q0B.x = q0.z; q0B.y = q0.w;
    f32x2 q1A; q1A.x = q1.x; q1A.y = q1.y;
    f32x2 q1B; q1B.x = q1.z; q1B.y = q1.w;
    accA = pk_fma_lo(q0A, wp[i], accA);   // k = 16+2i
    accA = pk_fma_hi(q1A, wp[i], accA);   // k = 17+2i
    accB = pk_fma_lo(q0B, wp[i], accB);
    accB = pk_fma_hi(q1B, wp[i], accB);
  }
  oA = accA; oB = accB;
}

// ---------------- stage 1: partial column sums of embedding ----------------
__global__ __launch_bounds__(512) void colsum_kernel(const float4* __restrict__ emb4,
                                                     float4* __restrict__ partials4,
                                                     int nblk) {
  __shared__ float4 red[4][128];
  const int t = threadIdx.x;
  const int c4 = t & 127, rs = t >> 7;
  float4 acc = make_float4(0.f, 0.f, 0.f, 0.f);
  const int stride = nblk * 4;
  for (int r = blockIdx.x * 4 + rs; r < BATCH; r += stride) {
    float4 v = emb4[(size_t)r * 128 + c4];
    acc.x += v.x; acc.y += v.y; acc.z += v.z; acc.w += v.w;
  }
  red[rs][c4] = acc;
  __syncthreads();
  if (rs == 0) {
    float4 a = red[0][c4], b = red[1][c4], c = red[2][c4], d = red[3][c4];
    float4 s;
    s.x = (a.x + b.x) + (c.x + d.x);
    s.y = (a.y + b.y) + (c.y + d.y);
    s.z = (a.z + b.z) + (c.z + d.z);
    s.w = (a.w + b.w) + (c.w + d.w);
    partials4[(size_t)blockIdx.x * 128 + c4] = s;
  }
}

// ---------------- stage 2: reduce nblk slots -> g2 slots ----------------
__global__ __launch_bounds__(512) void reduce_kernel(const float* __restrict__ partials,
                                                     float* __restrict__ level2, int per) {
  const int t = threadIdx.x;
  float a = 0.0f;
  const int s0 = blockIdx.x * per;
  for (int s = s0; s < s0 + per; ++s) a += partials[(size_t)s * EDIM + t];
  level2[(size_t)blockIdx.x * EDIM + t] = a;
}

// ---------------- stage 3: finish b, derive all threefry keys ----------------
__global__ __launch_bounds__(512) void prep_kernel(const float* __restrict__ pca,
                                                   const float* __restrict__ level2, int g2,
                                                   float* __restrict__ bvec,
                                                   unsigned* __restrict__ keys) {
  __shared__ float cs[EDIM];
  int t = threadIdx.x;
  float a = 0.0f;
  for (int i = 0; i < g2; ++i) a += level2[(size_t)i * EDIM + t];
  cs[t] = a;
  __syncthreads();
  if (t < NNODES) {
    float bj = 0.0f;
    if (t < NVIS) {
      for (int e = 0; e < EDIM; ++e) bj = fmaf(cs[e], pca[e * NVIS + t], bj);
      bj *= (1.0f / 65536.0f);
    }
    bvec[t] = bj;
  }
  if (t == 0) {
    uint32_t ki0, ki1, ks0, ks1;
    tf2x32(0u, 42u, 0u, 0u, ki0, ki1);          // k_init
    tf2x32(0u, 42u, 0u, 1u, ks0, ks1);          // k_scan
    keys[0] = ki0; keys[1] = ki1;
    for (int s = 0; s < NSTEPS; ++s) {
      uint32_t y0, y1;
      tf2x32(ks0, ks1, 0u, (uint32_t)s, y0, y1);
      keys[2 + 2 * s] = y0;
      keys[3 + 2 * s] = y1;
    }
  }
}

// ---------------- gibbs chain + energy: 1 wave = 4 rows, 3 ciphers/lane/step ----------
__global__ __launch_bounds__(256) void gibbs_kernel(const float* __restrict__ reward,
                                                    const float* __restrict__ quadratic,
                                                    const float* __restrict__ bvec,
                                                    const unsigned* __restrict__ keys,
                                                    float* __restrict__ out) {
#pragma clang fp contract(off)
  __shared__ float Wl[NNODES][NNODES];       // 16KB, read-only after prolog
  __shared__ float ubuf[4][4 * NHID];        // per-wave u staging [row][node'] (3KB)
  __shared__ f32x4 sbuf[4][NHID];            // per-wave state [node'] = {r0..r3} (3KB)

  const int tid = threadIdx.x;
  for (int i = tid; i < NNODES * NNODES; i += 256) {
    int k = i >> 6, j = i & 63;
    Wl[k][j] = quadratic[i] + quadratic[j * NNODES + k];  // exact f32 add
  }
  __syncthreads();

  const int wave = tid >> 6, lane = tid & 63;
  const int gw = blockIdx.x * 4 + wave;      // wave-global index
  const int r0 = gw * 4;                     // 4 consecutive rows per wave

  const float4 rw4 = ((const float4*)reward)[gw];
  const float bj = bvec[lane];
  f32x2 svA = sigmoid2_pk((f32x2){rw4.x * 2.0f, rw4.y * 2.0f});
  f32x2 svB = sigmoid2_pk((f32x2){rw4.z * 2.0f, rw4.w * 2.0f});

  // W column: hidden rows as pairs; visible prefix folded into acc16 (k=0..15 in order)
  f32x2 wp[24];
#pragma unroll
  for (int i = 0; i < 24; ++i) {
    f32x2 w; w.x = Wl[16 + 2 * i][lane]; w.y = Wl[17 + 2 * i][lane];
    wp[i] = w;
  }
  f32x2 acc16A = (f32x2)0.0f, acc16B = (f32x2)0.0f;
#pragma unroll
  for (int i = 0; i < 8; ++i) {
    f32x2 w; w.x = Wl[2 * i][lane]; w.y = Wl[2 * i + 1][lane];
    acc16A = pk_fma_lo(svA, w, acc16A);
    acc16A = pk_fma_hi(svA, w, acc16A);
    acc16B = pk_fma_lo(svB, w, acc16B);
    acc16B = pk_fma_hi(svB, w, acc16B);
  }

  // producer routing: draw idx = c*64 + lane -> (row rr, hidden node jj); step-invariant
  uint32_t nn[3];            // scan counters: (r0+rr)*64 + 16 + jj   (shape B x 64)
  float*   uw[3];            // ubuf write slots [rr][jj]
  float*   s0p[3];           // init state write slots [jj].component rr
  uint32_t ni[3];            // init counters: (r0+rr)*48 + jj        (shape B x 48)
#pragma unroll
  for (int c = 0; c < 3; ++c) {
    int idx = c * 64 + lane;
    int rr = (idx * 683) >> 15;            // idx / 48 for idx < 192
    int jj = idx - rr * 48;
    nn[c] = (uint32_t)((r0 + rr) * NNODES + NVIS + jj);
    ni[c] = (uint32_t)((r0 + rr) * NHID + jj);
    uw[c]  = &ubuf[wave][rr * NHID + jj];
    s0p[c] = ((float*)&sbuf[wave][0]) + (jj * 4 + rr);
  }

  // hidden0 = bernoulli(k_init, 0.5): bit = (rbits32 >> 31) == 0; 192 draws = 3 ciphers
  {
    const uint32_t ki0 = keys[0], ki1 = keys[1];
#pragma unroll
    for (int c = 0; c < 3; ++c) {
      uint32_t b = rbits32(ki0, ki1, ni[c]);
      *s0p[c] = (b >> 31) ? 0.0f : 1.0f;
    }
  }

  const bool isvis = (lane < NVIS);
  const int jc = isvis ? 0 : lane - NVIS;
  f32x2 scurA = svA, scurB = svB;          // visible lanes keep sv forever
  const float* ub = ubuf[wave];
  const f32x4* st = sbuf[wave];

  const uint2* kbuf = (const uint2*)(keys + 2);
  uint2 kk = kbuf[0];
#pragma unroll 1
  for (int t = 0; t < NSTEPS; ++t) {
    uint2 kn = kbuf[(t + 1 < NSTEPS) ? t + 1 : t];
    // 3 independent cipher chains (compiler interleaves for ILP)
    uint32_t b0 = rbits32(kk.x, kk.y, nn[0]);
    uint32_t b1 = rbits32(kk.x, kk.y, nn[1]);
    uint32_t b2 = rbits32(kk.x, kk.y, nn[2]);
    *uw[0] = __uint_as_float((b0 >> 9) | 0x3f800000u) - 1.0f;  // exact u01
    *uw[1] = __uint_as_float((b1 >> 9) | 0x3f800000u) - 1.0f;
    *uw[2] = __uint_as_float((b2 >> 9) | 0x3f800000u) - 1.0f;

    f32x2 aA, aB;
    dot4(st, wp, acc16A, acc16B, aA, aB);
    f32x2 pA = sigmoid2_pk(aA);            // b adds 0 to hidden units
    f32x2 pB = sigmoid2_pk(aB);

    f32x2 uA; uA.x = ub[jc];            uA.y = ub[NHID + jc];
    f32x2 uB; uB.x = ub[2 * NHID + jc]; uB.y = ub[3 * NHID + jc];
    if (!isvis) {
      scurA.x = (uA.x < pA.x) ? 1.0f : 0.0f;
      scurA.y = (uA.y < pA.y) ? 1.0f : 0.0f;
      scurB.x = (uB.x < pB.x) ? 1.0f : 0.0f;
      scurB.y = (uB.y < pB.y) ? 1.0f : 0.0f;
      f32x4 sq; sq.x = scurA.x; sq.y = scurA.y; sq.z = scurB.x; sq.w = scurB.y;
      sbuf[wave][jc] = sq;
    }
    kk = kn;
  }

  // energy: adjusted[r] = reward[r] + sum_j s_j*(0.5*a_j + b_j)   (loose tolerance)
  f32x2 aA, aB;
  dot4(st, wp, acc16A, acc16B, aA, aB);
  f32x2 bj2; bj2.x = bj; bj2.y = bj;
  const f32x2 half2 = (f32x2)0.5f;
  f32x2 cA = pk_mul2(scurA, pk_fma2(half2, aA, bj2));
  f32x2 cB = pk_mul2(scurB, pk_fma2(half2, aB, bj2));
  float c0 = cA.x, c1 = cA.y, c2 = cB.x, c3 = cB.y;
#pragma unroll
  for (int off = 32; off; off >>= 1) {
    c0 += __shfl_xor(c0, off);
    c1 += __shfl_xor(c1, off);
    c2 += __shfl_xor(c2, off);
    c3 += __shfl_xor(c3, off);
  }
  if (lane == 0) {
    ((float4*)out)[gw] = make_float4(rw4.x + c0, rw4.y + c1, rw4.z + c2, rw4.w + c3);
  }
}

extern "C" void kernel_launch(void* const* d_in, const int* in_sizes, int n_in,
                              void* d_out, int out_size, void* d_ws, size_t ws_size,
                              hipStream_t stream) {
  const float* emb    = (const float*)d_in[0];
  const float* reward = (const float*)d_in[1];
  const float* pca    = (const float*)d_in[2];
  const float* quad   = (const float*)d_in[3];
  float* out = (float*)d_out;

  int nblk = 1024;
  while (nblk > 4 &&
         ws_size < (size_t)nblk * EDIM * 4 + (size_t)64 * EDIM * 4 + 4096)
    nblk >>= 1;
  const int g2  = (nblk >= 64) ? 64 : nblk;
  const int per = nblk / g2;

  float*    partials = (float*)d_ws;
  float*    level2   = partials + (size_t)nblk * EDIM;
  float*    bvec     = level2 + (size_t)64 * EDIM;
  unsigned* keys     = (unsigned*)(bvec + NNODES);

  colsum_kernel<<<nblk, 512, 0, stream>>>((const float4*)emb, (float4*)partials, nblk);
  reduce_kernel<<<g2, 512, 0, stream>>>(partials, level2, per);
  prep_kernel<<<1, 512, 0, stream>>>(pca, level2, g2, bvec, keys);
  gibbs_kernel<<<BATCH / 16, 256, 0, stream>>>(reward, quad, bvec, keys, out);
}